// Round 1
// baseline (245.678 us; speedup 1.0000x reference)
//
#include <hip/hip_runtime.h>

typedef __attribute__((ext_vector_type(8))) short short8;
typedef __attribute__((ext_vector_type(4))) float f32x4;
typedef __attribute__((ext_vector_type(16))) float f32x16;

#define IMG_H 320
#define IMG_W 320
#define NBATCH 2
#define NFEAT 48
#define PLANE (IMG_H * IMG_W)          // 102400
#define KDIM 864                        // 9 taps * 96 channels
#define NDIM 96

// cconv tile params
#define TH 8
#define TW 32
#define BLK 512                         // 8 waves, one per tile row
#define HALO_H (TH + 2)                 // 10
#define HALO_W (TW + 2)                 // 34
#define HALO_PIX (HALO_H * HALO_W)      // 340
#define CPAD 104                        // 96 ch + 8 pad shorts per pixel row (208B, 16B aligned)
#define NCHUNK 12
#define STAGE_TOT (HALO_PIX * NCHUNK)   // 4080
#define EPAD 100                        // epilogue f32 transpose row stride (dwords)

__device__ __forceinline__ float sigma_f(float x) {
    float ax = __builtin_fabsf(x);
    float quad = x * x * 250.0f + 0.5f * x + 0.00025f;
    float rel = fmaxf(x, 0.0f);
    return ax > 0.001f ? rel : quad;
}

__device__ __forceinline__ unsigned short f2bf(float f) {
    union { float f; unsigned u; } v; v.f = f;
    unsigned r = (v.u + 0x7FFFu + ((v.u >> 16) & 1u)) >> 16;
    return (unsigned short)r;
}

// Both layers' Wt[n][k] bf16 in one launch. n<48 -> yr of f=n, else yi of f=n-48;
// k = tap*96 + cp (cp<48 -> real ch cp, else imag ch cp-48).
__global__ void wprep_kernel(const float* __restrict__ wr1, const float* __restrict__ wi1,
                             const float* __restrict__ wr2, const float* __restrict__ wi2,
                             unsigned short* __restrict__ wt1, unsigned short* __restrict__ wt2) {
    int idx = blockIdx.x * 256 + threadIdx.x;
    if (idx >= 2 * NDIM * KDIM) return;
    int which = idx >= NDIM * KDIM;
    int id = which ? idx - NDIM * KDIM : idx;
    const float* wr = which ? wr2 : wr1;
    const float* wi = which ? wi2 : wi1;
    unsigned short* wt = which ? wt2 : wt1;
    int n = id / KDIM;
    int k = id - n * KDIM;
    int tap = k / 96;
    int cp = k - tap * 96;
    int f = (n < 48) ? n : n - 48;
    int c = (cp < 48) ? cp : cp - 48;
    int widx = (f * 48 + c) * 9 + tap;   // [F][Cin][3][3]
    float v;
    if (n < 48) v = (cp < 48) ?  wr[widx] : -wi[widx];
    else        v = (cp < 48) ?  wi[widx] :  wr[widx];
    wt[id] = f2bf(v);
}

// Layer 0: 1->48 complex conv, thread-per-pixel over ALL f.
template<int OUT_NHWC>
__global__ __launch_bounds__(256) void layer0_kernel(
    const float* __restrict__ xr, const float* __restrict__ xi,
    const float* __restrict__ wr, const float* __restrict__ wi,
    const float* __restrict__ br, const float* __restrict__ bi,
    float* __restrict__ out, unsigned short* __restrict__ nhwc) {
    int idx = blockIdx.x * 256 + threadIdx.x;        // 204800 pixels total
    int b = idx / PLANE;
    int p = idx - b * PLANE;
    int h = p / IMG_W;
    int w = p - h * IMG_W;
    const float* xrp = xr + (size_t)b * PLANE;
    const float* xip = xi + (size_t)b * PLANE;

    float ar[9], ai[9];
#pragma unroll
    for (int dy = 0; dy < 3; ++dy) {
#pragma unroll
        for (int dx = 0; dx < 3; ++dx) {
            int hh = h + dy - 1, ww = w + dx - 1;
            bool ok = ((unsigned)hh < (unsigned)IMG_H) && ((unsigned)ww < (unsigned)IMG_W);
            ar[dy * 3 + dx] = ok ? xrp[hh * IMG_W + ww] : 0.0f;
            ai[dy * 3 + dx] = ok ? xip[hh * IMG_W + ww] : 0.0f;
        }
    }

    short8 nh[12];
#pragma unroll
    for (int f = 0; f < NFEAT; ++f) {
        float yr = br[f], yi = bi[f];
#pragma unroll
        for (int t = 0; t < 9; ++t) {
            float wrv = wr[f * 9 + t], wiv = wi[f * 9 + t];
            yr += ar[t] * wrv - ai[t] * wiv;
            yi += ar[t] * wiv + ai[t] * wrv;
        }
        float2 o; o.x = yr; o.y = yi;
        *reinterpret_cast<float2*>(out + ((size_t)(b * NFEAT + f) * PLANE + p) * 2) = o;
        if (OUT_NHWC) {
            nh[f >> 3][f & 7] = (short)f2bf(sigma_f(yr));
            nh[6 + (f >> 3)][f & 7] = (short)f2bf(sigma_f(yi));
        }
    }
    if (OUT_NHWC) {
        unsigned short* dst = nhwc + (size_t)(b * PLANE + p) * 96;
#pragma unroll
        for (int c = 0; c < 12; ++c)
            *reinterpret_cast<short8*>(dst + c * 8) = nh[c];
    }
}

// Layers 1/2: implicit-GEMM complex conv 48->48, bf16 MFMA 32x32x16.
// 8 waves, wave w owns output tile row w (32 pixels) x all 96 N-cols (3 frags).
// IN_MODE: 0 = fp32 interleaved pre-act (sigma on load), 1 = bf16 NHWC post-act.
template<int IN_MODE, int OUT_NHWC>
__global__ __launch_bounds__(BLK, 4) void cconv_kernel(
    const float* __restrict__ inF, const unsigned short* __restrict__ inH,
    const unsigned short* __restrict__ wt,   // [96][864] bf16
    const float* __restrict__ br, const float* __restrict__ bi,
    float* __restrict__ outF, unsigned short* __restrict__ outH) {
    __shared__ __align__(16) unsigned short tile[HALO_PIX * CPAD];  // 70720 B

    // XCD-aware swizzle: grid = 800 = 8 * 100, bijective chunked remap
    int bid0 = blockIdx.x;
    int bid = (bid0 & 7) * 100 + (bid0 >> 3);
    int wblk = bid % (IMG_W / TW);          // 10
    int t = bid / (IMG_W / TW);
    int hblk = t % (IMG_H / TH);            // 40
    int b = t / (IMG_H / TH);
    int h0 = hblk * TH, w0 = wblk * TW;

    int tid = threadIdx.x;

    // ---- stage halo tile; per-pixel 12 chunks of 8ch, chunk idx XOR-swizzled
    //      by (pix>>3)&3 to break the stride-52-dword bank-window aliasing ----
    if (IN_MODE == 1) {
        const unsigned short* inHb = inH + (size_t)b * PLANE * 96;
        short8 v[8];
        int dst[8];
#pragma unroll
        for (int s = 0; s < 8; ++s) {
            int it = tid + s * BLK;
            int pix = it / NCHUNK;
            int chunk = it - pix * NCHUNK;
            int hh = pix / HALO_W;
            int ww = pix - hh * HALO_W;
            int h = h0 + hh - 1, w = w0 + ww - 1;
            bool inimg = ((unsigned)h < (unsigned)IMG_H) && ((unsigned)w < (unsigned)IMG_W);
            bool live = it < STAGE_TOT;
            int sc = chunk ^ ((pix >> 3) & 3);
            dst[s] = live ? (pix * CPAD + sc * 8) : -1;
            if (live && inimg)
                v[s] = *reinterpret_cast<const short8*>(
                    inHb + ((size_t)(h * IMG_W + w) * 96 + chunk * 8));
            else
                v[s] = (short8){0, 0, 0, 0, 0, 0, 0, 0};
        }
#pragma unroll
        for (int s = 0; s < 8; ++s)
            if (dst[s] >= 0) *reinterpret_cast<short8*>(&tile[dst[s]]) = v[s];
    } else {
        const float* inFb = inF + (size_t)b * NFEAT * PLANE * 2;
        for (int it = tid; it < STAGE_TOT; it += BLK) {
            int pix = it / NCHUNK;
            int chunk = it - pix * NCHUNK;
            int hh = pix / HALO_W;
            int ww = pix - hh * HALO_W;
            int h = h0 + hh - 1, w = w0 + ww - 1;
            bool ok = ((unsigned)h < (unsigned)IMG_H) && ((unsigned)w < (unsigned)IMG_W);
            int c0 = chunk * 8;
            short8 v;
#pragma unroll
            for (int j = 0; j < 8; ++j) {
                int cp = c0 + j;
                int c = (cp < 48) ? cp : cp - 48;
                int ri = (cp < 48) ? 0 : 1;
                float x = ok ? inFb[((size_t)c * PLANE + h * IMG_W + w) * 2 + ri] : 0.0f;
                v[j] = (short)f2bf(sigma_f(x));
            }
            int sc = chunk ^ ((pix >> 3) & 3);
            *reinterpret_cast<short8*>(&tile[pix * CPAD + sc * 8]) = v;
        }
    }
    __syncthreads();

    int wave = tid >> 6, lane = tid & 63;
    int l31 = lane & 31, lk5 = lane >> 5;
    int base = wave * HALO_W + l31;         // halo pixel at tap (0,0) for (row=wave, col=l31)

    const unsigned short* wrow[3];
#pragma unroll
    for (int g = 0; g < 3; ++g)
        wrow[g] = wt + (size_t)(g * 32 + l31) * KDIM + lk5 * 8;

    f32x16 acc[3];
#pragma unroll
    for (int g = 0; g < 3; ++g)
#pragma unroll
        for (int r = 0; r < 16; ++r) acc[g][r] = 0.0f;

    // double-buffered B prefetch over 54 (tap, ks) K=16 steps
    short8 bf[2][3];
#pragma unroll
    for (int g = 0; g < 3; ++g)
        bf[0][g] = *reinterpret_cast<const short8*>(wrow[g]);

#pragma unroll
    for (int it = 0; it < 54; ++it) {
        const int cur = it & 1;
        const int tap = it / 6, ks = it - tap * 6;
        if (it < 53) {
            const int it2 = it + 1;
            const int tap2 = it2 / 6, ks2 = it2 - tap2 * 6;
#pragma unroll
            for (int g = 0; g < 3; ++g)
                bf[cur ^ 1][g] = *reinterpret_cast<const short8*>(wrow[g] + tap2 * 96 + ks2 * 16);
        }
        const int p = base + (tap / 3) * HALO_W + (tap % 3);
        const int c16 = (ks * 2 + lk5) ^ ((p >> 3) & 3);   // matches staging swizzle
        short8 a = *reinterpret_cast<const short8*>(&tile[p * CPAD + c16 * 8]);
#pragma unroll
        for (int g = 0; g < 3; ++g)
            acc[g] = __builtin_amdgcn_mfma_f32_32x32x16_bf16(a, bf[cur][g], acc[g], 0, 0, 0);
    }

    // ---- epilogue ----
    // D mapping (32x32): col n = l31 (+g*32), row m = (r&3) + 8*(r>>2) + 4*lk5.
    // Bias in-register, then 2 pixel-half rounds through LDS [128 pix][EPAD] f32:
    // fp32 out float2-coalesced, NHWC short8-coalesced.
#pragma unroll
    for (int g = 0; g < 3; ++g) {
        int n = g * 32 + l31;
        float bias = (n < NFEAT) ? br[n] : bi[n - NFEAT];
#pragma unroll
        for (int r = 0; r < 16; ++r) acc[g][r] += bias;
    }

    float* tf = reinterpret_cast<float*>(tile);
    __syncthreads();            // all A-reads done before reusing tile

#pragma unroll
    for (int half = 0; half < 2; ++half) {
        if ((wave >> 2) == half) {
            int rl = wave & 3;
#pragma unroll
            for (int g = 0; g < 3; ++g)
#pragma unroll
                for (int r = 0; r < 16; ++r) {
                    int m = (r & 3) + 8 * (r >> 2) + 4 * lk5;
                    tf[(rl * 32 + m) * EPAD + g * 32 + l31] = acc[g][r];
                }
        }
        __syncthreads();
        // fp32 out: 128 pix x 48 f float2 = 6144 -> 12 per thread, w-coalesced
#pragma unroll
        for (int j = 0; j < 12; ++j) {
            int idx = j * BLK + tid;
            int f = idx >> 7;
            int pl = idx & 127;
            float2 o;
            o.x = tf[pl * EPAD + f];
            o.y = tf[pl * EPAD + NFEAT + f];
            int h = h0 + half * 4 + (pl >> 5);
            int w = w0 + (pl & 31);
            *reinterpret_cast<float2*>(outF + (((size_t)(b * NFEAT + f) * IMG_H + h) * IMG_W + w) * 2) = o;
        }
        if (OUT_NHWC) {
            // 128 pix x 12 chunks short8 = 1536 -> 3 per thread, chunk-coalesced
#pragma unroll
            for (int jj = 0; jj < 3; ++jj) {
                int idx = jj * BLK + tid;
                int pl = idx / 12;
                int chunk = idx - pl * 12;
                const float* src = &tf[pl * EPAD + chunk * 8];
                short8 v;
#pragma unroll
                for (int u = 0; u < 8; ++u) v[u] = (short)f2bf(sigma_f(src[u]));
                int h = h0 + half * 4 + (pl >> 5);
                int w = w0 + (pl & 31);
                *reinterpret_cast<short8*>(
                    outH + ((size_t)(b * PLANE + h * IMG_W + w) * 96 + chunk * 8)) = v;
            }
        }
        if (half == 0) __syncthreads();
    }
}

extern "C" void kernel_launch(void* const* d_in, const int* in_sizes, int n_in,
                              void* d_out, int out_size, void* d_ws, size_t ws_size,
                              hipStream_t stream) {
    const float* x_real  = (const float*)d_in[0];
    const float* x_imag  = (const float*)d_in[1];
    const float* w0_real = (const float*)d_in[2];
    const float* w0_imag = (const float*)d_in[3];
    const float* b0_real = (const float*)d_in[4];
    const float* b0_imag = (const float*)d_in[5];
    const float* w1_real = (const float*)d_in[6];
    const float* w1_imag = (const float*)d_in[7];
    const float* b1_real = (const float*)d_in[8];
    const float* b1_imag = (const float*)d_in[9];
    const float* w2_real = (const float*)d_in[10];
    const float* w2_imag = (const float*)d_in[11];
    const float* b2_real = (const float*)d_in[12];
    const float* b2_imag = (const float*)d_in[13];

    float* out = (float*)d_out;
    unsigned short* wt1 = (unsigned short*)d_ws;
    unsigned short* wt2 = wt1 + NDIM * KDIM;

    const size_t wt_bytes = (size_t)2 * NDIM * KDIM * 2;             // 331776
    const size_t nhwc_elems = (size_t)NBATCH * PLANE * 96;           // 19,660,800 bf16
    const size_t need = wt_bytes + 2 * nhwc_elems * 2;               // ~75.3 MiB
    const bool fast = ws_size >= need;

    unsigned short* nhwc0 = (unsigned short*)((char*)d_ws + wt_bytes);
    unsigned short* nhwc1 = nhwc0 + nhwc_elems;

    const size_t layer_sz = (size_t)NBATCH * NFEAT * PLANE * 2;      // floats per layer

    wprep_kernel<<<(2 * NDIM * KDIM + 255) / 256, 256, 0, stream>>>(
        w1_real, w1_imag, w2_real, w2_imag, wt1, wt2);

    const int l0_grid = NBATCH * PLANE / 256;                        // 800
    const int conv_grid = NBATCH * (IMG_H / TH) * (IMG_W / TW);      // 800

    if (fast) {
        layer0_kernel<1><<<l0_grid, 256, 0, stream>>>(
            x_real, x_imag, w0_real, w0_imag, b0_real, b0_imag, out, nhwc0);
        cconv_kernel<1, 1><<<conv_grid, BLK, 0, stream>>>(
            nullptr, nhwc0, wt1, b1_real, b1_imag, out + layer_sz, nhwc1);
        cconv_kernel<1, 0><<<conv_grid, BLK, 0, stream>>>(
            nullptr, nhwc1, wt2, b2_real, b2_imag, out + 2 * layer_sz, nullptr);
    } else {
        layer0_kernel<0><<<l0_grid, 256, 0, stream>>>(
            x_real, x_imag, w0_real, w0_imag, b0_real, b0_imag, out, nullptr);
        cconv_kernel<0, 0><<<conv_grid, BLK, 0, stream>>>(
            out, nullptr, wt1, b1_real, b1_imag, out + layer_sz, nullptr);
        cconv_kernel<0, 0><<<conv_grid, BLK, 0, stream>>>(
            out + layer_sz, nullptr, wt2, b2_real, b2_imag, out + 2 * layer_sz, nullptr);
    }
}